// Round 11
// baseline (225.378 us; speedup 1.0000x reference)
//
#include <hip/hip_runtime.h>
#include <stdint.h>

// Problem constants (B=2, L=8, N=1024, DIM=512, H=8, DH=64)
#define DIMC 512
#define NSEQ 1024
#define BLT  16        // B*L
#define NHEAD 8
#define DHD  64
#define MTOT (BLT*NSEQ)   // 16384 rows

typedef float f32x4 __attribute__((ext_vector_type(4)));
typedef float f32x16 __attribute__((ext_vector_type(16)));
typedef short s16x8 __attribute__((ext_vector_type(8)));
typedef short s16x4 __attribute__((ext_vector_type(4)));

__device__ __forceinline__ unsigned short f2bf(float f) {
    unsigned int u = __float_as_uint(f);
    u += 0x7fffu + ((u >> 16) & 1u);   // RNE
    return (unsigned short)(u >> 16);
}
__device__ __forceinline__ float bf2f(unsigned short h) {
    return __uint_as_float(((unsigned int)h) << 16);
}

// softmax pre-scale: 1/sqrt(512) * log2(e)  (exp2-domain softmax)
#define QSCALE (0.04419417382415922f * 1.4426950408889634f)

// async global->LDS, 16B per lane. lds base must be wave-uniform.
__device__ __forceinline__ void gll16(const void* g, void* l) {
    __builtin_amdgcn_global_load_lds(
        (const __attribute__((address_space(1))) void*)g,
        (__attribute__((address_space(3))) void*)l, 16, 0, 0);
}

// pack 2 f32 -> u32 of 2 bf16 (RNE), low = first arg
__device__ __forceinline__ unsigned int cvtpk(float lo, float hi) {
    unsigned int r;
    asm("v_cvt_pk_bf16_f32 %0, %1, %2" : "=v"(r) : "v"(lo), "v"(hi));
    return r;
}

// v_permlane32_swap_b32 a, b
__device__ __forceinline__ void pl32swap(unsigned int &a, unsigned int &b) {
    asm volatile("v_permlane32_swap_b32 %0, %1" : "+v"(a), "+v"(b));
}

// inline dtype detect: wave ballot over "crazy bf16 exponent" in x's first 128B
__device__ __forceinline__ bool detect_bf16(const unsigned short* x) {
    int t = threadIdx.x & 63;
    unsigned short v = x[2 * t];
    int e = (v >> 7) & 0xFF;
    unsigned long long ball = __ballot(e < 100 || e > 137);
    return __popcll(ball) < 16;
}

// ---------------------------------------------------------------------------
// Fused QKV projection (R17): conversion fused into staging — NO conv pass.
// z=0: Q (pre-scaled, [bh][n][d]); z=1: K <- x@Wv^T+bv (FAITHFUL BUG);
// z=2: Vt <- x@Wk^T+bk stored KEYSLOT-MAJOR [bh][n>>5][(n>>3)&3][d][8keys].
// Staging: if input bf16 -> gll16 (linear); if f32 -> reg-stage float4x2 ->
// 4x v_cvt_pk_bf16_f32 (RNE, == f2bf) -> ds_write_b128 at the SAME LDS
// address the gll16 path uses. Biases read in-place (f32 or bf16).
// 1D grid, XCD-bijective swizzle (1536 = 8*192; mt%8 == xcd; nt fastest).
// ---------------------------------------------------------------------------
__global__ __launch_bounds__(256) void proj_kernel(
    const void* __restrict__ xr,
    const void* __restrict__ Wqr, const void* __restrict__ Wkr,
    const void* __restrict__ Wvr,
    const void* __restrict__ bqr, const void* __restrict__ bkr,
    const void* __restrict__ bvr,
    unsigned short* __restrict__ Q, unsigned short* __restrict__ K,
    unsigned short* __restrict__ Vt)
{
    const bool isbf = detect_bf16((const unsigned short*)xr);
    const int bid = blockIdx.x;
    const int xcd = bid & 7;
    const int s = bid >> 3;            // 0..191
    const int z = s >> 6;              // 0..2
    const int r = s & 63;              // 0..63
    const int mt = ((r >> 2) << 3) + xcd;   // 0..127
    const int nt = r & 3;

    const void* Wr = (z == 0) ? Wqr : ((z == 1) ? Wvr : Wkr);  // bug mapping
    const void* br = (z == 0) ? bqr : ((z == 1) ? bvr : bkr);
    unsigned short* outp = (z == 0) ? Q : ((z == 1) ? K : Vt);
    const float oscale = (z == 0) ? QSCALE : 1.0f;

    const int mBase = mt * 128;
    const int nBase = nt * 128;
    const int tid = threadIdx.x;
    const int wave = tid >> 6;
    const int lane = tid & 63;
    const int lr = lane & 15, lg = lane >> 4;
    const int wm = wave >> 1, wn = wave & 1;
    const int srow = lane >> 3;
    const int scol = (lane & 7) * 8;

    __shared__ unsigned short Al[128 * 64];
    __shared__ unsigned short Bl[128 * 64];

    f32x4 acc[4][4];
    #pragma unroll
    for (int a = 0; a < 4; ++a)
        #pragma unroll
        for (int b = 0; b < 4; ++b) acc[a][b] = (f32x4){0.f, 0.f, 0.f, 0.f};

    for (int k0 = 0; k0 < DIMC; k0 += 64) {
        if (isbf) {
            const unsigned short* xu = (const unsigned short*)xr;
            const unsigned short* Wu = (const unsigned short*)Wr;
            #pragma unroll
            for (int i = 0; i < 4; ++i) {
                int rbase = (wave * 4 + i) * 8;
                gll16(xu + (long)(mBase + rbase + srow) * DIMC + k0 + scol, Al + rbase * 64);
                gll16(Wu + (long)(nBase + rbase + srow) * DIMC + k0 + scol, Bl + rbase * 64);
            }
        } else {
            const float* xf = (const float*)xr;
            const float* Wf = (const float*)Wr;
            #pragma unroll
            for (int i = 0; i < 4; ++i) {
                int row = (wave * 4 + i) * 8 + srow;
                const float* ap = xf + (long)(mBase + row) * DIMC + k0 + scol;
                float4 a0 = *(const float4*)ap;
                float4 a1 = *(const float4*)(ap + 4);
                uint4 pa;
                pa.x = cvtpk(a0.x, a0.y); pa.y = cvtpk(a0.z, a0.w);
                pa.z = cvtpk(a1.x, a1.y); pa.w = cvtpk(a1.z, a1.w);
                *(uint4*)&Al[row * 64 + scol] = pa;
                const float* wp_ = Wf + (long)(nBase + row) * DIMC + k0 + scol;
                float4 b0 = *(const float4*)wp_;
                float4 b1 = *(const float4*)(wp_ + 4);
                uint4 pb;
                pb.x = cvtpk(b0.x, b0.y); pb.y = cvtpk(b0.z, b0.w);
                pb.z = cvtpk(b1.x, b1.y); pb.w = cvtpk(b1.z, b1.w);
                *(uint4*)&Bl[row * 64 + scol] = pb;
            }
        }
        __syncthreads();

        #pragma unroll
        for (int kk = 0; kk < 64; kk += 32) {
            s16x8 af[4], bf_[4];
            #pragma unroll
            for (int a = 0; a < 4; ++a)
                af[a] = *(const s16x8*)&Al[(wm * 64 + a * 16 + lr) * 64 + kk + lg * 8];
            #pragma unroll
            for (int b = 0; b < 4; ++b)
                bf_[b] = *(const s16x8*)&Bl[(wn * 64 + b * 16 + lr) * 64 + kk + lg * 8];
            #pragma unroll
            for (int a = 0; a < 4; ++a)
                #pragma unroll
                for (int b = 0; b < 4; ++b)
                    acc[a][b] = __builtin_amdgcn_mfma_f32_16x16x32_bf16(af[a], bf_[b], acc[a][b], 0, 0, 0);
        }
        __syncthreads();
    }

    #pragma unroll
    for (int b = 0; b < 4; ++b) {
        int j = nBase + wn * 64 + b * 16 + lr;
        float bb = isbf ? bf2f(((const unsigned short*)br)[j]) : ((const float*)br)[j];
        int h = j >> 6, d = j & 63;
        #pragma unroll
        for (int a = 0; a < 4; ++a) {
            int m0 = mBase + wm * 64 + a * 16 + lg * 4;
            int bl = m0 >> 10, n0 = m0 & 1023;
            if (z == 2) {
                // keyslot-major: [n>>5][(n>>3)&3][d][n&7]; n0&7 in {0,4}
                ushort4 pk;
                unsigned short* p = (unsigned short*)&pk;
                #pragma unroll
                for (int r2 = 0; r2 < 4; ++r2) p[r2] = f2bf(acc[a][b][r2] + bb);
                int base = (((bl << 3) + h) << 16) + ((n0 >> 5) << 11)
                         + (((n0 >> 3) & 3) << 9) + (d << 3) + (n0 & 7);
                *(ushort4*)&outp[base] = pk;
            } else {
                #pragma unroll
                for (int r2 = 0; r2 < 4; ++r2) {
                    float v = (acc[a][b][r2] + bb) * oscale;
                    outp[(((bl << 3) + h) << 16) + ((n0 + r2) << 6) + d] = f2bf(v);
                }
            }
        }
    }
}

// ---------------------------------------------------------------------------
// Final projection (R17): out = inter @ Wo^T + bo. A (inter) is always bf16
// (attn output) -> gll16; B (Wo) dual-path staging; bias/output dtype dual.
// XCD-bijective swizzle (512 = 8 * 64).
// ---------------------------------------------------------------------------
__global__ __launch_bounds__(256) void out_gemm_kernel(
    const unsigned short* __restrict__ inter, const void* __restrict__ Wor,
    const void* __restrict__ bor, void* __restrict__ outp,
    const unsigned short* __restrict__ xdet)
{
    const bool isbf = detect_bf16(xdet);
    const int bid = blockIdx.x;
    const int xcd = bid & 7;
    const int s = bid >> 3;                 // 0..63
    const int mt = ((s >> 2) << 3) + xcd;   // 0..127
    const int nt = s & 3;

    const int mBase = mt * 128;
    const int nBase = nt * 128;
    const int tid = threadIdx.x;
    const int wave = tid >> 6;
    const int lane = tid & 63;
    const int lr = lane & 15, lg = lane >> 4;
    const int wm = wave >> 1, wn = wave & 1;
    const int srow = lane >> 3;
    const int scol = (lane & 7) * 8;

    __shared__ unsigned short Al[128 * 64];
    __shared__ unsigned short Bl[128 * 64];

    f32x4 acc[4][4];
    #pragma unroll
    for (int a = 0; a < 4; ++a)
        #pragma unroll
        for (int b = 0; b < 4; ++b) acc[a][b] = (f32x4){0.f, 0.f, 0.f, 0.f};

    for (int k0 = 0; k0 < DIMC; k0 += 64) {
        #pragma unroll
        for (int i = 0; i < 4; ++i) {
            int rbase = (wave * 4 + i) * 8;
            gll16(inter + (long)(mBase + rbase + srow) * DIMC + k0 + scol, Al + rbase * 64);
        }
        if (isbf) {
            const unsigned short* Wu = (const unsigned short*)Wor;
            #pragma unroll
            for (int i = 0; i < 4; ++i) {
                int rbase = (wave * 4 + i) * 8;
                gll16(Wu + (long)(nBase + rbase + srow) * DIMC + k0 + scol, Bl + rbase * 64);
            }
        } else {
            const float* Wf = (const float*)Wor;
            #pragma unroll
            for (int i = 0; i < 4; ++i) {
                int row = (wave * 4 + i) * 8 + srow;
                const float* wp_ = Wf + (long)(nBase + row) * DIMC + k0 + scol;
                float4 b0 = *(const float4*)wp_;
                float4 b1 = *(const float4*)(wp_ + 4);
                uint4 pb;
                pb.x = cvtpk(b0.x, b0.y); pb.y = cvtpk(b0.z, b0.w);
                pb.z = cvtpk(b1.x, b1.y); pb.w = cvtpk(b1.z, b1.w);
                *(uint4*)&Bl[row * 64 + scol] = pb;
            }
        }
        __syncthreads();

        #pragma unroll
        for (int kk = 0; kk < 64; kk += 32) {
            s16x8 af[4], bf_[4];
            #pragma unroll
            for (int a = 0; a < 4; ++a)
                af[a] = *(const s16x8*)&Al[(wm * 64 + a * 16 + lr) * 64 + kk + lg * 8];
            #pragma unroll
            for (int b = 0; b < 4; ++b)
                bf_[b] = *(const s16x8*)&Bl[(wn * 64 + b * 16 + lr) * 64 + kk + lg * 8];
            #pragma unroll
            for (int a = 0; a < 4; ++a)
                #pragma unroll
                for (int b = 0; b < 4; ++b)
                    acc[a][b] = __builtin_amdgcn_mfma_f32_16x16x32_bf16(af[a], bf_[b], acc[a][b], 0, 0, 0);
        }
        __syncthreads();
    }

    #pragma unroll
    for (int b = 0; b < 4; ++b) {
        int j = nBase + wn * 64 + b * 16 + lr;
        float bb = isbf ? bf2f(((const unsigned short*)bor)[j]) : ((const float*)bor)[j];
        #pragma unroll
        for (int a = 0; a < 4; ++a) {
            #pragma unroll
            for (int r = 0; r < 4; ++r) {
                long m = mBase + wm * 64 + a * 16 + lg * 4 + r;
                float v = acc[a][b][r] + bb;
                if (isbf) ((unsigned short*)outp)[m * DIMC + j] = f2bf(v);
                else      ((float*)outp)[m * DIMC + j] = v;
            }
        }
    }
}

// ---------------------------------------------------------------------------
// Flash attention (R8 structure, R13 V path — unchanged, ~61us):
// full-rate 32x32x16 MFMA, permlane32_swap P redistribution, ones-MFMA
// l-sum, persistent zero16, dbuf K/V LDS, one barrier/kt.
//  - K: pre-swizzled-source staging (involution XOR), conflict-free reads.
//  - V: keyslot-major global -> linear staging, contiguous 1KB b128 reads.
// blockIdx = qt*128 + bh -> XCD = bh%8.
// ---------------------------------------------------------------------------
#define SWZ(row, col) ((row) * 64 + ((col) ^ (((row) & 7) * 8)))

__global__ __launch_bounds__(256, 3) void attn_kernel(
    const unsigned short* __restrict__ Q, const unsigned short* __restrict__ K,
    const unsigned short* __restrict__ Vt, unsigned short* __restrict__ inter)
{
    const int b = blockIdx.x;          // 0..1023
    const int bh = b & 127;            // XCD = bh % 8  (L2 locality)
    const int qt = b >> 7;             // 0..7 (128-q tile)
    const int tid = threadIdx.x;
    const int wave = tid >> 6;
    const int lane = tid & 63;
    const int l31 = lane & 31;
    const int hi = lane >> 5;

    const unsigned short* Qb = Q + (long)bh * (NSEQ * DHD);
    const int qbase = qt * 128 + wave * 32;

    // Q B-frags (32x32x16): lane holds Q[q = qbase+l31][k16*16 + hi*8 + 0..7]
    s16x8 qf[4];
    #pragma unroll
    for (int k16 = 0; k16 < 4; ++k16)
        qf[k16] = *(const s16x8*)&Qb[(qbase + l31) * DHD + k16 * 16 + hi * 8];

    __shared__ unsigned short Kl[2][64 * 64];   // [buf][key][d], swizzled content
    __shared__ unsigned short Vl[2][64 * 64];   // [buf]: 2x4KB keyslot-major chunks

    // K staging: per-lane PRE-SWIZZLED global source; linear gll16 dest.
    const int srow = tid >> 3;
    const int scol = ((tid & 7) * 8) ^ ((srow & 7) * 8);
    const unsigned short* kp = K  + (long)bh * (NSEQ * DHD) + srow * DHD + scol;
    // V staging: keyslot-major global is already tile-linear.
    const unsigned short* vg = Vt + (long)bh * (NSEQ * DHD);

    auto stage = [&](int buf, int kt) {
        unsigned short* Kb_ = &Kl[buf][0];
        unsigned short* Vb_ = &Vl[buf][0];
        const long ko = (long)kt * 4096;
        gll16(kp + ko,                                Kb_ + wave * 512);
        gll16(kp + ko + 2048,                         Kb_ + wave * 512 + 2048);
        gll16(vg + ko + wave * 512 + lane * 8,        Vb_ + wave * 512);
        gll16(vg + ko + 2048 + wave * 512 + lane * 8, Vb_ + wave * 512 + 2048);
    };

    f32x16 o[2];     // O^T: lane holds O^T[dt*32 + (r&3)+8*(r>>2)+4*hi][q=l31]
    f32x16 lacc;     // ones-MFMA row-sums: every reg = l[q=l31]
    f32x16 zero16;   // persistent zero C-operand (kills per-kc init movs)
    #pragma unroll
    for (int r = 0; r < 16; ++r) { o[0][r] = 0.f; o[1][r] = 0.f; lacc[r] = 0.f; zero16[r] = 0.f; }
    const s16x8 ones8 = {(short)0x3F80, (short)0x3F80, (short)0x3F80, (short)0x3F80,
                         (short)0x3F80, (short)0x3F80, (short)0x3F80, (short)0x3F80};

    stage(0, 0);
    __syncthreads();   // implicit vmcnt(0) drain -> tile 0 resident

    #pragma unroll 2
    for (int kt = 0; kt < 16; ++kt) {
        const int cur = kt & 1;
        if (kt < 15)   // prefetch next tile into the other buffer (no wait)
            stage(cur ^ 1, kt + 1);

        const unsigned short* Kc = &Kl[cur][0];
        const unsigned short* Vc = &Vl[cur][0];

        #pragma unroll
        for (int kc = 0; kc < 2; ++kc) {
            // S^T[key][q] = K.Q^T over this 32-key chunk, K=64 in 4 steps
            s16x8 af[4];
            #pragma unroll
            for (int k16 = 0; k16 < 4; ++k16)
                af[k16] = *(const s16x8*)&Kc[SWZ(kc * 32 + l31, k16 * 16 + hi * 8)];
            f32x16 s;
            __builtin_amdgcn_s_setprio(1);
            s = __builtin_amdgcn_mfma_f32_32x32x16_bf16(af[0], qf[0], zero16, 0, 0, 0);
            s = __builtin_amdgcn_mfma_f32_32x32x16_bf16(af[1], qf[1], s, 0, 0, 0);
            s = __builtin_amdgcn_mfma_f32_32x32x16_bf16(af[2], qf[2], s, 0, 0, 0);
            s = __builtin_amdgcn_mfma_f32_32x32x16_bf16(af[3], qf[3], s, 0, 0, 0);
            __builtin_amdgcn_s_setprio(0);

            // P^T = exp2(S^T); pack; key-half redistribution via permlane32_swap.
            float p[16];
            #pragma unroll
            for (int r = 0; r < 16; ++r) p[r] = __builtin_exp2f(s[r]);
            unsigned int w[4][2];
            #pragma unroll
            for (int b4 = 0; b4 < 4; ++b4) {
                w[b4][0] = cvtpk(p[4 * b4 + 0], p[4 * b4 + 1]);
                w[b4][1] = cvtpk(p[4 * b4 + 2], p[4 * b4 + 3]);
            }
            s16x8 frag[2];
            #pragma unroll
            for (int t16 = 0; t16 < 2; ++t16) {
                unsigned int a0 = w[2 * t16][0], b0 = w[2 * t16 + 1][0];
                unsigned int a1 = w[2 * t16][1], b1 = w[2 * t16 + 1][1];
                pl32swap(a0, b0);
                pl32swap(a1, b1);
                union { unsigned int u[4]; s16x8 v; } f;
                f.u[0] = a0; f.u[1] = a1; f.u[2] = b0; f.u[3] = b1;
                frag[t16] = f.v;
            }

            // l += row-sums (ones-MFMA); O^T += V^T.P^T
            s16x8 va[2][2];
            #pragma unroll
            for (int dt = 0; dt < 2; ++dt)
                #pragma unroll
                for (int t16 = 0; t16 < 2; ++t16)
                    va[dt][t16] = *(const s16x8*)&Vc[kc * 2048 + (t16 * 2 + hi) * 512
                                                     + (dt * 32 + l31) * 8];
            __builtin_amdgcn_s_setprio(1);
            lacc = __builtin_amdgcn_mfma_f32_32x32x16_bf16(ones8, frag[0], lacc, 0, 0, 0);
            lacc = __builtin_amdgcn_mfma_f32_32x32x16_bf16(ones8, frag[1], lacc, 0, 0, 0);
            #pragma unroll
            for (int dt = 0; dt < 2; ++dt)
                #pragma unroll
                for (int t16 = 0; t16 < 2; ++t16)
                    o[dt] = __builtin_amdgcn_mfma_f32_32x32x16_bf16(va[dt][t16], frag[t16], o[dt], 0, 0, 0);
            __builtin_amdgcn_s_setprio(0);
        }

        if (kt < 15) __syncthreads();  // drains prefetch vmcnt + releases buffer
    }

    // epilogue: every lane holds full l in lacc[*]; normalize, store merged-head.
    const int bl = bh >> 3, h = bh & 7;
    const int q = qbase + l31;
    float inv = 1.f / lacc[0];
    #pragma unroll
    for (int dt = 0; dt < 2; ++dt) {
        #pragma unroll
        for (int b4 = 0; b4 < 4; ++b4) {
            unsigned int w0 = cvtpk(o[dt][4 * b4 + 0] * inv, o[dt][4 * b4 + 1] * inv);
            unsigned int w1 = cvtpk(o[dt][4 * b4 + 2] * inv, o[dt][4 * b4 + 3] * inv);
            union { unsigned int u[2]; ushort4 v; } pk;
            pk.u[0] = w0; pk.u[1] = w1;
            *(ushort4*)&inter[((long)(bl * NSEQ + q)) * DIMC + h * 64 + dt * 32 + 8 * b4 + 4 * hi] = pk.v;
        }
    }
}

// ---------------------------------------------------------------------------
extern "C" void kernel_launch(void* const* d_in, const int* in_sizes, int n_in,
                              void* d_out, int out_size, void* d_ws, size_t ws_size,
                              hipStream_t stream) {
    const void* x  = d_in[0];
    const void* Wq = d_in[1]; const void* bq = d_in[2];
    const void* Wk = d_in[3]; const void* bk = d_in[4];
    const void* Wv = d_in[5]; const void* bv = d_in[6];
    const void* Wo = d_in[7]; const void* bo = d_in[8];

    char* ws = (char*)d_ws;
    unsigned short* inter = (unsigned short*)ws;
    unsigned short* Q   = inter + (long)MTOT * DIMC;
    unsigned short* K   = Q  + (long)MTOT * DIMC;
    unsigned short* Vt  = K  + (long)MTOT * DIMC;

    proj_kernel<<<1536, 256, 0, stream>>>(x, Wq, Wk, Wv, bq, bk, bv, Q, K, Vt);

    attn_kernel<<<8 * 128, 256, 0, stream>>>(Q, K, Vt, inter);

    out_gemm_kernel<<<512, 256, 0, stream>>>(inter, Wo, bo, d_out,
                                             (const unsigned short*)x);
}

// Round 12
// 207.066 us; speedup vs baseline: 1.0884x; 1.0884x over previous
//
#include <hip/hip_runtime.h>
#include <stdint.h>

// Problem constants (B=2, L=8, N=1024, DIM=512, H=8, DH=64)
#define DIMC 512
#define NSEQ 1024
#define BLT  16        // B*L
#define NHEAD 8
#define DHD  64
#define MTOT (BLT*NSEQ)   // 16384 rows

typedef float f32x4 __attribute__((ext_vector_type(4)));
typedef float f32x16 __attribute__((ext_vector_type(16)));
typedef short s16x8 __attribute__((ext_vector_type(8)));
typedef short s16x4 __attribute__((ext_vector_type(4)));

__device__ __forceinline__ unsigned short f2bf(float f) {
    unsigned int u = __float_as_uint(f);
    u += 0x7fffu + ((u >> 16) & 1u);   // RNE
    return (unsigned short)(u >> 16);
}
__device__ __forceinline__ float bf2f(unsigned short h) {
    return __uint_as_float(((unsigned int)h) << 16);
}

// softmax pre-scale: 1/sqrt(512) * log2(e)  (exp2-domain softmax)
#define QSCALE (0.04419417382415922f * 1.4426950408889634f)

// async global->LDS, 16B per lane. lds base must be wave-uniform.
__device__ __forceinline__ void gll16(const void* g, void* l) {
    __builtin_amdgcn_global_load_lds(
        (const __attribute__((address_space(1))) void*)g,
        (__attribute__((address_space(3))) void*)l, 16, 0, 0);
}

// pack 2 f32 -> u32 of 2 bf16 (RNE), low = first arg
__device__ __forceinline__ unsigned int cvtpk(float lo, float hi) {
    unsigned int r;
    asm("v_cvt_pk_bf16_f32 %0, %1, %2" : "=v"(r) : "v"(lo), "v"(hi));
    return r;
}

// v_permlane32_swap_b32 a, b
__device__ __forceinline__ void pl32swap(unsigned int &a, unsigned int &b) {
    asm volatile("v_permlane32_swap_b32 %0, %1" : "+v"(a), "+v"(b));
}

// inline dtype detect: wave ballot over "crazy bf16 exponent" in x's first 128B
__device__ __forceinline__ bool detect_bf16(const unsigned short* x) {
    int t = threadIdx.x & 63;
    unsigned short v = x[2 * t];
    int e = (v >> 7) & 0xFF;
    unsigned long long ball = __ballot(e < 100 || e > 137);
    return __popcll(ball) < 16;
}

// ---------------------------------------------------------------------------
// One-time convert of all inputs to bf16 (straight copy if already bf16).
// R11 lesson: fusing this into proj costs VGPR/occupancy + f32 re-reads;
// the standalone pass is cheaper. Keep it.
// ---------------------------------------------------------------------------
struct ConvArgs {
    const void* src[9];
    unsigned short* dst[9];
};

__global__ __launch_bounds__(256) void conv_kernel(ConvArgs a,
                                                   const unsigned short* __restrict__ xdet) {
    const bool isbf = detect_bf16(xdet);
    int b = blockIdx.x;
    int seg, idx;
    if (b < 4096)      { seg = 0; idx = (b * 256 + threadIdx.x) * 8; }
    else if (b < 4608) { int t = b - 4096; seg = 1 + (t >> 7);
                         idx = (((t & 127) * 256) + threadIdx.x) * 8; }
    else               { int i = threadIdx.x * 8; seg = 5 + (i >> 9); idx = i & 511; }
    const void* s = a.src[seg];
    unsigned short* d = a.dst[seg];
    if (isbf) {
        *(uint4*)(d + idx) = *(const uint4*)((const unsigned short*)s + idx);
    } else {
        float4 t0 = *(const float4*)((const float*)s + idx);
        float4 t1 = *(const float4*)((const float*)s + idx + 4);
        ushort4 v0{f2bf(t0.x), f2bf(t0.y), f2bf(t0.z), f2bf(t0.w)};
        ushort4 v1{f2bf(t1.x), f2bf(t1.y), f2bf(t1.z), f2bf(t1.w)};
        *(ushort4*)(d + idx)     = v0;
        *(ushort4*)(d + idx + 4) = v1;
    }
}

// ---------------------------------------------------------------------------
// Fused QKV projection (R18): 256x128 tile (R8's best-bench config), 8 waves
// (512 thr), wave-tile 64x64 — now DOUBLE-BUFFERED at BK=32 with the SAME
// 48KB LDS footprint (2 x 24KB). Per K-step each wave issues 3 gll16 for the
// NEXT buffer BEFORE computing the current one; ONE barrier per step (its
// implicit vmcnt(0) drain is the prefetch wait). R8's BK=64 single-buffer
// serialized stage->barrier->compute (MfmaUtil 14%, m233 stall regime).
// Bonus: 64B rows alternate bank-halves -> frag reads spread all 32 banks.
// z=0: Q (pre-scaled, [bh][n][d]); z=1: K <- x@Wv^T+bv (FAITHFUL BUG);
// z=2: Vt <- x@Wk^T+bk stored KEYSLOT-MAJOR [bh][n>>5][(n>>3)&3][d][8keys].
// 1D grid, XCD-bijective swizzle (768 = 8*96; mt%8 == xcd; nt fastest).
// ---------------------------------------------------------------------------
__global__ __launch_bounds__(512) void proj_kernel(
    const unsigned short* __restrict__ xb,
    const unsigned short* __restrict__ Wqb, const unsigned short* __restrict__ Wkb,
    const unsigned short* __restrict__ Wvb,
    const unsigned short* __restrict__ bqb, const unsigned short* __restrict__ bkb,
    const unsigned short* __restrict__ bvb,
    unsigned short* __restrict__ Q, unsigned short* __restrict__ K,
    unsigned short* __restrict__ Vt)
{
    const int bid = blockIdx.x;            // 0..767
    const int xcd = bid & 7;
    const int s = bid >> 3;                // 0..95
    const int z = s >> 5;                  // 0..2
    const int r = s & 31;                  // 0..31
    const int mt = ((r >> 2) << 3) + xcd;  // 0..63
    const int nt = r & 3;
    const int mBase = mt * 256;
    const int nBase = nt * 128;

    const unsigned short* Wp = (z == 0) ? Wqb : ((z == 1) ? Wvb : Wkb);  // bug mapping
    const unsigned short* bp = (z == 0) ? bqb : ((z == 1) ? bvb : bkb);
    unsigned short* outp = (z == 0) ? Q : ((z == 1) ? K : Vt);
    const float oscale = (z == 0) ? QSCALE : 1.0f;

    const int tid = threadIdx.x;           // 0..511
    const int wave = tid >> 6;             // 0..7
    const int lane = tid & 63;
    const int lr = lane & 15, lg = lane >> 4;
    const int wm = wave >> 1, wn = wave & 1;   // 4 x 2 wave grid

    // BK=32 rows are 32 shorts (64B). One gll16 (1KB/wave) covers 16 rows.
    const int srow = lane >> 2;            // 0..15
    const int scol = (lane & 3) * 8;

    __shared__ unsigned short Al[2 * 256 * 32];   // 32 KB (2 x 16KB)
    __shared__ unsigned short Bl[2 * 128 * 32];   // 16 KB (2 x 8KB)

    f32x4 acc[4][4];
    #pragma unroll
    for (int a = 0; a < 4; ++a)
        #pragma unroll
        for (int b = 0; b < 4; ++b) acc[a][b] = (f32x4){0.f, 0.f, 0.f, 0.f};

    auto stage = [&](int buf, int k0) {
        unsigned short* Ab = Al + buf * 8192;
        unsigned short* Bb = Bl + buf * 4096;
        // A: wave stages rows [wave*32, +16) then [wave*32+16, +16)
        gll16(xb + (long)(mBase + wave * 32 + srow) * DIMC + k0 + scol,
              Ab + wave * 1024);
        gll16(xb + (long)(mBase + wave * 32 + 16 + srow) * DIMC + k0 + scol,
              Ab + wave * 1024 + 512);
        // B: wave stages rows [wave*16, +16)
        gll16(Wp + (long)(nBase + wave * 16 + srow) * DIMC + k0 + scol,
              Bb + wave * 512);
    };

    stage(0, 0);
    __syncthreads();   // implicit vmcnt(0) drain -> K-step 0 resident

    #pragma unroll 2
    for (int k = 0; k < 16; ++k) {
        const int cur = k & 1;
        if (k < 15) stage(cur ^ 1, (k + 1) * 32);   // prefetch, no wait

        const unsigned short* Ac = Al + cur * 8192;
        const unsigned short* Bc = Bl + cur * 4096;
        s16x8 af[4], bf_[4];
        #pragma unroll
        for (int a = 0; a < 4; ++a)
            af[a] = *(const s16x8*)&Ac[(wm * 64 + a * 16 + lr) * 32 + lg * 8];
        #pragma unroll
        for (int b = 0; b < 4; ++b)
            bf_[b] = *(const s16x8*)&Bc[(wn * 64 + b * 16 + lr) * 32 + lg * 8];
        #pragma unroll
        for (int a = 0; a < 4; ++a)
            #pragma unroll
            for (int b = 0; b < 4; ++b)
                acc[a][b] = __builtin_amdgcn_mfma_f32_16x16x32_bf16(af[a], bf_[b], acc[a][b], 0, 0, 0);

        if (k < 15) __syncthreads();  // drains prefetch vmcnt + releases buffer
    }

    #pragma unroll
    for (int b = 0; b < 4; ++b) {
        int j = nBase + wn * 64 + b * 16 + lr;
        float bb = bf2f(bp[j]);
        int h = j >> 6, d = j & 63;
        #pragma unroll
        for (int a = 0; a < 4; ++a) {
            int m0 = mBase + wm * 64 + a * 16 + lg * 4;
            int bl = m0 >> 10, n0 = m0 & 1023;
            if (z == 2) {
                // keyslot-major: [n>>5][(n>>3)&3][d][n&7]; n0&7 in {0,4}
                ushort4 pk;
                unsigned short* p = (unsigned short*)&pk;
                #pragma unroll
                for (int r2 = 0; r2 < 4; ++r2) p[r2] = f2bf(acc[a][b][r2] + bb);
                int base = (((bl << 3) + h) << 16) + ((n0 >> 5) << 11)
                         + (((n0 >> 3) & 3) << 9) + (d << 3) + (n0 & 7);
                *(ushort4*)&outp[base] = pk;
            } else {
                #pragma unroll
                for (int r2 = 0; r2 < 4; ++r2) {
                    float v = (acc[a][b][r2] + bb) * oscale;
                    outp[(((bl << 3) + h) << 16) + ((n0 + r2) << 6) + d] = f2bf(v);
                }
            }
        }
    }
}

// ---------------------------------------------------------------------------
// m97-pattern GEMM core (for out_gemm): 128x128 tile, BK=64,
// global_load_lds width=16. 4 waves in 2x2; each wave 4x4 of 16x16x32 MFMA.
// ---------------------------------------------------------------------------
__device__ __forceinline__ void gemm_core_async(
    const unsigned short* __restrict__ Ap, const unsigned short* __restrict__ Wp,
    int mBase, int nBase, unsigned short* Al, unsigned short* Bl, f32x4 acc[4][4])
{
    const int wave = threadIdx.x >> 6;
    const int lane = threadIdx.x & 63;
    const int lr = lane & 15, lg = lane >> 4;
    const int wm = wave >> 1, wn = wave & 1;
    const int srow = lane >> 3;
    const int scol = (lane & 7) * 8;

    #pragma unroll
    for (int a = 0; a < 4; ++a)
        #pragma unroll
        for (int b = 0; b < 4; ++b) acc[a][b] = (f32x4){0.f, 0.f, 0.f, 0.f};

    for (int k0 = 0; k0 < DIMC; k0 += 64) {
        #pragma unroll
        for (int i = 0; i < 4; ++i) {
            int rbase = (wave * 4 + i) * 8;
            gll16(Ap + (long)(mBase + rbase + srow) * DIMC + k0 + scol, Al + rbase * 64);
            gll16(Wp + (long)(nBase + rbase + srow) * DIMC + k0 + scol, Bl + rbase * 64);
        }
        __syncthreads();

        #pragma unroll
        for (int kk = 0; kk < 64; kk += 32) {
            s16x8 af[4], bf_[4];
            #pragma unroll
            for (int a = 0; a < 4; ++a)
                af[a] = *(const s16x8*)&Al[(wm * 64 + a * 16 + lr) * 64 + kk + lg * 8];
            #pragma unroll
            for (int b = 0; b < 4; ++b)
                bf_[b] = *(const s16x8*)&Bl[(wn * 64 + b * 16 + lr) * 64 + kk + lg * 8];
            #pragma unroll
            for (int a = 0; a < 4; ++a)
                #pragma unroll
                for (int b = 0; b < 4; ++b)
                    acc[a][b] = __builtin_amdgcn_mfma_f32_16x16x32_bf16(af[a], bf_[b], acc[a][b], 0, 0, 0);
        }
        __syncthreads();
    }
}

// ---------------------------------------------------------------------------
// Final projection: out = inter @ Wo^T + bo, output dtype via inline detect.
// XCD-bijective swizzle (512 = 8 * 64) for inter-panel L2 reuse.
// ---------------------------------------------------------------------------
__global__ __launch_bounds__(256) void out_gemm_kernel(
    const unsigned short* __restrict__ inter, const unsigned short* __restrict__ Wob,
    const unsigned short* __restrict__ bob, void* __restrict__ outp,
    const unsigned short* __restrict__ xdet)
{
    const bool isbf = detect_bf16(xdet);
    const int bid = blockIdx.x;
    const int xcd = bid & 7;
    const int s = bid >> 3;                 // 0..63
    const int mt = ((s >> 2) << 3) + xcd;   // 0..127
    const int nt = s & 3;

    const int mBase = mt * 128;
    const int nBase = nt * 128;
    const int lane = threadIdx.x & 63;
    const int lr = lane & 15, lg = lane >> 4;
    const int wm = (threadIdx.x >> 6) >> 1, wn = (threadIdx.x >> 6) & 1;

    __shared__ unsigned short Al[128 * 64];
    __shared__ unsigned short Bl[128 * 64];
    f32x4 acc[4][4];
    gemm_core_async(inter, Wob, mBase, nBase, Al, Bl, acc);

    #pragma unroll
    for (int b = 0; b < 4; ++b) {
        int j = nBase + wn * 64 + b * 16 + lr;
        float bb = bf2f(bob[j]);
        #pragma unroll
        for (int a = 0; a < 4; ++a) {
            #pragma unroll
            for (int r = 0; r < 4; ++r) {
                long m = mBase + wm * 64 + a * 16 + lg * 4 + r;
                float v = acc[a][b][r] + bb;
                if (isbf) ((unsigned short*)outp)[m * DIMC + j] = f2bf(v);
                else      ((float*)outp)[m * DIMC + j] = v;
            }
        }
    }
}

// ---------------------------------------------------------------------------
// Flash attention (R8 structure, R13 V path — unchanged, ~61us plateau):
// full-rate 32x32x16 MFMA, permlane32_swap P redistribution, ones-MFMA
// l-sum, persistent zero16, dbuf K/V LDS, one barrier/kt.
//  - K: pre-swizzled-source staging (involution XOR), conflict-free reads.
//  - V: keyslot-major global -> linear staging, contiguous 1KB b128 reads.
// blockIdx = qt*128 + bh -> XCD = bh%8.
// ---------------------------------------------------------------------------
#define SWZ(row, col) ((row) * 64 + ((col) ^ (((row) & 7) * 8)))

__global__ __launch_bounds__(256, 3) void attn_kernel(
    const unsigned short* __restrict__ Q, const unsigned short* __restrict__ K,
    const unsigned short* __restrict__ Vt, unsigned short* __restrict__ inter)
{
    const int b = blockIdx.x;          // 0..1023
    const int bh = b & 127;            // XCD = bh % 8  (L2 locality)
    const int qt = b >> 7;             // 0..7 (128-q tile)
    const int tid = threadIdx.x;
    const int wave = tid >> 6;
    const int lane = tid & 63;
    const int l31 = lane & 31;
    const int hi = lane >> 5;

    const unsigned short* Qb = Q + (long)bh * (NSEQ * DHD);
    const int qbase = qt * 128 + wave * 32;

    // Q B-frags (32x32x16): lane holds Q[q = qbase+l31][k16*16 + hi*8 + 0..7]
    s16x8 qf[4];
    #pragma unroll
    for (int k16 = 0; k16 < 4; ++k16)
        qf[k16] = *(const s16x8*)&Qb[(qbase + l31) * DHD + k16 * 16 + hi * 8];

    __shared__ unsigned short Kl[2][64 * 64];   // [buf][key][d], swizzled content
    __shared__ unsigned short Vl[2][64 * 64];   // [buf]: 2x4KB keyslot-major chunks

    // K staging: per-lane PRE-SWIZZLED global source; linear gll16 dest.
    const int srow = tid >> 3;
    const int scol = ((tid & 7) * 8) ^ ((srow & 7) * 8);
    const unsigned short* kp = K  + (long)bh * (NSEQ * DHD) + srow * DHD + scol;
    // V staging: keyslot-major global is already tile-linear.
    const unsigned short* vg = Vt + (long)bh * (NSEQ * DHD);

    auto stage = [&](int buf, int kt) {
        unsigned short* Kb_ = &Kl[buf][0];
        unsigned short* Vb_ = &Vl[buf][0];
        const long ko = (long)kt * 4096;
        gll16(kp + ko,                                Kb_ + wave * 512);
        gll16(kp + ko + 2048,                         Kb_ + wave * 512 + 2048);
        gll16(vg + ko + wave * 512 + lane * 8,        Vb_ + wave * 512);
        gll16(vg + ko + 2048 + wave * 512 + lane * 8, Vb_ + wave * 512 + 2048);
    };

    f32x16 o[2];     // O^T: lane holds O^T[dt*32 + (r&3)+8*(r>>2)+4*hi][q=l31]
    f32x16 lacc;     // ones-MFMA row-sums: every reg = l[q=l31]
    f32x16 zero16;   // persistent zero C-operand (kills per-kc init movs)
    #pragma unroll
    for (int r = 0; r < 16; ++r) { o[0][r] = 0.f; o[1][r] = 0.f; lacc[r] = 0.f; zero16[r] = 0.f; }
    const s16x8 ones8 = {(short)0x3F80, (short)0x3F80, (short)0x3F80, (short)0x3F80,
                         (short)0x3F80, (short)0x3F80, (short)0x3F80, (short)0x3F80};

    stage(0, 0);
    __syncthreads();   // implicit vmcnt(0) drain -> tile 0 resident

    #pragma unroll 2
    for (int kt = 0; kt < 16; ++kt) {
        const int cur = kt & 1;
        if (kt < 15)   // prefetch next tile into the other buffer (no wait)
            stage(cur ^ 1, kt + 1);

        const unsigned short* Kc = &Kl[cur][0];
        const unsigned short* Vc = &Vl[cur][0];

        #pragma unroll
        for (int kc = 0; kc < 2; ++kc) {
            // S^T[key][q] = K.Q^T over this 32-key chunk, K=64 in 4 steps
            s16x8 af[4];
            #pragma unroll
            for (int k16 = 0; k16 < 4; ++k16)
                af[k16] = *(const s16x8*)&Kc[SWZ(kc * 32 + l31, k16 * 16 + hi * 8)];
            f32x16 s;
            __builtin_amdgcn_s_setprio(1);
            s = __builtin_amdgcn_mfma_f32_32x32x16_bf16(af[0], qf[0], zero16, 0, 0, 0);
            s = __builtin_amdgcn_mfma_f32_32x32x16_bf16(af[1], qf[1], s, 0, 0, 0);
            s = __builtin_amdgcn_mfma_f32_32x32x16_bf16(af[2], qf[2], s, 0, 0, 0);
            s = __builtin_amdgcn_mfma_f32_32x32x16_bf16(af[3], qf[3], s, 0, 0, 0);
            __builtin_amdgcn_s_setprio(0);

            // P^T = exp2(S^T); pack; key-half redistribution via permlane32_swap.
            float p[16];
            #pragma unroll
            for (int r = 0; r < 16; ++r) p[r] = __builtin_exp2f(s[r]);
            unsigned int w[4][2];
            #pragma unroll
            for (int b4 = 0; b4 < 4; ++b4) {
                w[b4][0] = cvtpk(p[4 * b4 + 0], p[4 * b4 + 1]);
                w[b4][1] = cvtpk(p[4 * b4 + 2], p[4 * b4 + 3]);
            }
            s16x8 frag[2];
            #pragma unroll
            for (int t16 = 0; t16 < 2; ++t16) {
                unsigned int a0 = w[2 * t16][0], b0 = w[2 * t16 + 1][0];
                unsigned int a1 = w[2 * t16][1], b1 = w[2 * t16 + 1][1];
                pl32swap(a0, b0);
                pl32swap(a1, b1);
                union { unsigned int u[4]; s16x8 v; } f;
                f.u[0] = a0; f.u[1] = a1; f.u[2] = b0; f.u[3] = b1;
                frag[t16] = f.v;
            }

            // l += row-sums (ones-MFMA); O^T += V^T.P^T
            s16x8 va[2][2];
            #pragma unroll
            for (int dt = 0; dt < 2; ++dt)
                #pragma unroll
                for (int t16 = 0; t16 < 2; ++t16)
                    va[dt][t16] = *(const s16x8*)&Vc[kc * 2048 + (t16 * 2 + hi) * 512
                                                     + (dt * 32 + l31) * 8];
            __builtin_amdgcn_s_setprio(1);
            lacc = __builtin_amdgcn_mfma_f32_32x32x16_bf16(ones8, frag[0], lacc, 0, 0, 0);
            lacc = __builtin_amdgcn_mfma_f32_32x32x16_bf16(ones8, frag[1], lacc, 0, 0, 0);
            #pragma unroll
            for (int dt = 0; dt < 2; ++dt)
                #pragma unroll
                for (int t16 = 0; t16 < 2; ++t16)
                    o[dt] = __builtin_amdgcn_mfma_f32_32x32x16_bf16(va[dt][t16], frag[t16], o[dt], 0, 0, 0);
            __builtin_amdgcn_s_setprio(0);
        }

        if (kt < 15) __syncthreads();  // drains prefetch vmcnt + releases buffer
    }

    // epilogue: every lane holds full l in lacc[*]; normalize, store merged-head.
    const int bl = bh >> 3, h = bh & 7;
    const int q = qbase + l31;
    float inv = 1.f / lacc[0];
    #pragma unroll
    for (int dt = 0; dt < 2; ++dt) {
        #pragma unroll
        for (int b4 = 0; b4 < 4; ++b4) {
            unsigned int w0 = cvtpk(o[dt][4 * b4 + 0] * inv, o[dt][4 * b4 + 1] * inv);
            unsigned int w1 = cvtpk(o[dt][4 * b4 + 2] * inv, o[dt][4 * b4 + 3] * inv);
            union { unsigned int u[2]; ushort4 v; } pk;
            pk.u[0] = w0; pk.u[1] = w1;
            *(ushort4*)&inter[((long)(bl * NSEQ + q)) * DIMC + h * 64 + dt * 32 + 8 * b4 + 4 * hi] = pk.v;
        }
    }
}

// ---------------------------------------------------------------------------
extern "C" void kernel_launch(void* const* d_in, const int* in_sizes, int n_in,
                              void* d_out, int out_size, void* d_ws, size_t ws_size,
                              hipStream_t stream) {
    const void* x  = d_in[0];
    const void* Wq = d_in[1]; const void* bq = d_in[2];
    const void* Wk = d_in[3]; const void* bk = d_in[4];
    const void* Wv = d_in[5]; const void* bv = d_in[6];
    const void* Wo = d_in[7]; const void* bo = d_in[8];

    char* ws = (char*)d_ws;
    unsigned short* xb  = (unsigned short*)ws;              // also 'inter' (aliased)
    unsigned short* Q   = xb + (long)MTOT * DIMC;
    unsigned short* K   = Q  + (long)MTOT * DIMC;
    unsigned short* Vt  = K  + (long)MTOT * DIMC;
    unsigned short* Wqb = Vt + (long)MTOT * DIMC;
    unsigned short* Wkb = Wqb + DIMC * DIMC;
    unsigned short* Wvb = Wkb + DIMC * DIMC;
    unsigned short* Wob = Wvb + DIMC * DIMC;
    unsigned short* bqb = Wob + DIMC * DIMC;
    unsigned short* bkb = bqb + DIMC;
    unsigned short* bvb = bkb + DIMC;
    unsigned short* bob = bvb + DIMC;

    ConvArgs ca;
    ca.src[0] = x;  ca.src[1] = Wq; ca.src[2] = Wk; ca.src[3] = Wv; ca.src[4] = Wo;
    ca.src[5] = bq; ca.src[6] = bk; ca.src[7] = bv; ca.src[8] = bo;
    ca.dst[0] = xb;  ca.dst[1] = Wqb; ca.dst[2] = Wkb; ca.dst[3] = Wvb; ca.dst[4] = Wob;
    ca.dst[5] = bqb; ca.dst[6] = bkb; ca.dst[7] = bvb; ca.dst[8] = bob;
    conv_kernel<<<4609, 256, 0, stream>>>(ca, (const unsigned short*)x);

    proj_kernel<<<768, 512, 0, stream>>>(xb, Wqb, Wkb, Wvb, bqb, bkb, bvb, Q, K, Vt);

    attn_kernel<<<8 * 128, 256, 0, stream>>>(Q, K, Vt, xb /*inter*/);

    out_gemm_kernel<<<512, 256, 0, stream>>>(xb /*inter*/, Wob, bob, d_out,
                                             (const unsigned short*)x);
}